// Round 6
// baseline (275.750 us; speedup 1.0000x reference)
//
#include <hip/hip_runtime.h>

#define NB 1024
#define NS 1024
#define NT 32
#define L2E 1.44269504088896340736f
#define LN2 0.69314718055994530942f

typedef short        bfrag  __attribute__((ext_vector_type(8)));   // 8 bf16 (4 VGPR)
typedef float        cfrag  __attribute__((ext_vector_type(16)));  // 16 f32 acc
typedef __bf16       bf16x2 __attribute__((ext_vector_type(2)));
typedef float        f32x2  __attribute__((ext_vector_type(2)));
typedef unsigned int u32;
typedef unsigned int u32x2v __attribute__((ext_vector_type(2)));
typedef unsigned int u32x4  __attribute__((ext_vector_type(4)));

__device__ __forceinline__ float fexp2(float x){ return __builtin_amdgcn_exp2f(x); }
__device__ __forceinline__ float flog2(float x){ return __builtin_amdgcn_logf(x); }

// truncation pack: single v_perm_b32. low16 = bf16_trunc(a), high16 = bf16_trunc(b).
__device__ __forceinline__ u32 pkbf_t(float a, float b){
    return __builtin_amdgcn_perm(__builtin_bit_cast(u32, b),
                                 __builtin_bit_cast(u32, a), 0x07060302u);
}

#if __has_builtin(__builtin_amdgcn_permlane32_swap)
#define HAVE_PLSWAP 1
#else
#define HAVE_PLSWAP 0
#endif

// after call: x_new = {x.lo32, y.lo32}, y_new = {x.hi32, y.hi32}
__device__ __forceinline__ void half_swap(u32 &x, u32 &y, int h){
#if HAVE_PLSWAP
    u32x2v r = __builtin_amdgcn_permlane32_swap(x, y, false, false);
    x = r[0]; y = r[1];
#else
    u32 X  = __shfl_xor(h ? x : y, 32, 64);
    u32 nx = h ? X : x;
    u32 ny = h ? y : X;
    x = nx; y = ny;
#endif
}

template<int N> struct ic { static constexpr int value = N; };
union accu { cfrag c; f32x2 p[8]; };

// ---------------- Phase 1: per-(batch,chunk) 32x32 transfer matrix ----------------
// M <- (D_t E^T) @ M. D folded into the A-operand: row m's scale d_t[m] is lane m's
// OWN register (exp2 of its loaded emission) -> ZERO LDS, no barriers. Et held as
// fp32 pairs; A built per step with 8 pk_mul + 8 perm-packs. Renorm fully deferred:
// exponent detect (SALU) at i=3/7, applied as fma addend in the next step's exp2.
// launch_bounds(256,4): 128 regs/wave -> no AGPR shuttle traffic.
__global__ __launch_bounds__(256, 4) void crf_chunk(
    const float* __restrict__ logits, const float* __restrict__ trans,
    u32* __restrict__ wmat, float* __restrict__ woff)
{
    const int tid = threadIdx.x;
    const int wv  = tid >> 6, lt = tid & 63;
    const int m   = lt & 31,  h  = lt >> 5;
    const int bc  = blockIdx.x * 4 + wv;
    const int b   = bc >> 3,  c  = bc & 7;

    const int tbeg = c*128 + 1;
    const int L    = (c == 7) ? 127 : 128;
    const int Lm1  = L - 1;
    const float* p = logits + (size_t)b * NS * NT + (size_t)tbeg * NT + m;

    // Et in fp32 pairs: Et0p[d] = {E^T[m][8h+2d], E^T[m][8h+2d+1]}, Et1p: +16 on k
    f32x2 Et0p[4], Et1p[4];
    #pragma unroll
    for (int d = 0; d < 4; d++){
        Et0p[d].x = fexp2(L2E * trans[(     8*h + 2*d    )*NT + m]);
        Et0p[d].y = fexp2(L2E * trans[(     8*h + 2*d + 1)*NT + m]);
        Et1p[d].x = fexp2(L2E * trans[(16 + 8*h + 2*d    )*NT + m]);
        Et1p[d].y = fexp2(L2E * trans[(16 + 8*h + 2*d + 1)*NT + m]);
    }

    // B = identity (packed bf16): B[k][n], n=lane&31, dword d covers k = 8h+2d(+1) (+16)
    u32x4 B0v, B1v;
    #pragma unroll
    for (int d = 0; d < 4; d++){
        int k0 = 8*h + 2*d;      u32 v = 0;
        if (k0     == m) v |= 0x3F80u;
        if (k0 + 1 == m) v |= 0x3F800000u;
        B0v[d] = v;
        int k1 = 16 + 8*h + 2*d; v = 0;
        if (k1     == m) v |= 0x3F80u;
        if (k1 + 1 == m) v |= 0x3F800000u;
        B1v[d] = v;
    }

    cfrag zacc;
    #pragma unroll
    for (int q = 0; q < 16; q++) zacc[q] = 0.0f;

    int   offi = 0;        // accumulated log2 scale (wave-uniform integer)
    float adj  = 0.0f;     // pending renorm, folded into next applied step's exp2

    float e0[8], e1[8], e2[8];
    auto loadblk = [&](float (&e)[8], int k){
        #pragma unroll
        for (int i = 0; i < 8; i++){
            int t = k*8 + i; t = t > Lm1 ? Lm1 : t;   // clamp c==7 tail
            e[i] = p[t*NT];
        }
    };

    auto procblk = [&](float (&e)[8], bool last, auto nstc){
        constexpr int NST = decltype(nstc)::value;
        #pragma unroll
        for (int i = 0; i < NST; i++){
            // d_t[m] for this lane's A rows; slots 0/4 carry the deferred renorm
            float dval = (i == 0 || i == 4) ? fexp2(fmaf(L2E, e[i], adj))
                                            : fexp2(L2E * e[i]);
            f32x2 ds; ds.x = dval; ds.y = dval;
            u32x4 a0, a1;
            #pragma unroll
            for (int d = 0; d < 4; d++){
                f32x2 t0 = Et0p[d] * ds;  a0[d] = pkbf_t(t0.x, t0.y);
                f32x2 t1 = Et1p[d] * ds;  a1[d] = pkbf_t(t1.x, t1.y);
            }
            accu acc;
            acc.c = __builtin_amdgcn_mfma_f32_32x32x16_bf16(
                        __builtin_bit_cast(bfrag, a0),
                        __builtin_bit_cast(bfrag, B0v), zacc, 0, 0, 0);
            acc.c = __builtin_amdgcn_mfma_f32_32x32x16_bf16(
                        __builtin_bit_cast(bfrag, a1),
                        __builtin_bit_cast(bfrag, B1v), acc.c, 0, 0, 0);

            // renorm detect: power-of-2, wave-uniform, applied via next exp2 (free)
            if (i == 3 || (i == 7 && !last)){
                float ref = fmaxf(acc.c[0], acc.c[8]);
                u32 xf = __builtin_amdgcn_readfirstlane(__builtin_bit_cast(u32, ref));
                int ex = (int)((xf >> 23) & 0xFFu) - 127;
                ex = ex < -120 ? -120 : (ex > 120 ? 120 : ex);
                offi += ex;
                adj = -(float)ex;
            }

            // pack C/D -> bf16 (truncation, 1 v_perm each), half-swap to B layout
            u32 P0 = pkbf_t(acc.c[0],  acc.c[1]),  P1 = pkbf_t(acc.c[2],  acc.c[3]);
            u32 P2 = pkbf_t(acc.c[4],  acc.c[5]),  P3 = pkbf_t(acc.c[6],  acc.c[7]);
            u32 P4 = pkbf_t(acc.c[8],  acc.c[9]),  P5 = pkbf_t(acc.c[10], acc.c[11]);
            u32 P6 = pkbf_t(acc.c[12], acc.c[13]), P7 = pkbf_t(acc.c[14], acc.c[15]);
            half_swap(P0, P2, h); half_swap(P1, P3, h);
            half_swap(P4, P6, h); half_swap(P5, P7, h);
            B0v[0]=P0; B0v[1]=P1; B0v[2]=P2; B0v[3]=P3;
            B1v[0]=P4; B1v[1]=P5; B1v[2]=P6; B1v[3]=P7;
        }
    };

    // 16 blocks of 8 steps; 3-buffer ring, loads issued 2 blocks ahead
    loadblk(e0, 0); loadblk(e1, 1);
    #pragma unroll 1
    for (int k = 0; k < 15; k += 3){
        loadblk(e2, k + 2);
        procblk(e0, false, ic<8>{});
        if (k + 3 < 16) loadblk(e0, k + 3);
        procblk(e1, false, ic<8>{});
        if (k + 4 < 16) loadblk(e1, k + 4);
        procblk(e2, false, ic<8>{});
    }
    // block 15 (loaded into e0 at k=12)
    if (c != 7) procblk(e0, true, ic<8>{});
    else        procblk(e0, true, ic<7>{});

    // store MT in B-frag form: wmat[bc*512 + d*64 + lane]
    const size_t mb = (size_t)bc * 512;
    #pragma unroll
    for (int d = 0; d < 4; d++){
        wmat[mb + d*64 + lt]     = B0v[d];
        wmat[mb + (4+d)*64 + lt] = B1v[d];
    }
    if (lt == 0) woff[bc] = (float)offi;
}

// ---------------- Phase 2: per-batch combine + full gold score ----------------
__global__ __launch_bounds__(64) void crf_combine(
    const float* __restrict__ logits, const float* __restrict__ trans,
    const int* __restrict__ tags, const int* __restrict__ lens,
    const u32* __restrict__ wmat, const float* __restrict__ woff,
    float* __restrict__ out)
{
    __shared__ __align__(16) float ldsT[NT*NT];
    __shared__ __align__(16) int   ldsTag[NS];
    __shared__ __align__(16) float ldsU[NT];

    const int tid = threadIdx.x;
    const int m   = tid & 31;
    const int b   = blockIdx.x;
    const int len = lens[b];
    const float* lgb = logits + (size_t)b * NS * NT;

    #pragma unroll
    for (int i = 0; i < 16; i++) ldsT[tid + i*64] = trans[tid + i*64];
    const int4* tg4 = (const int4*)(tags + b*NS);
    #pragma unroll
    for (int i = 0; i < 4; i++) ((int4*)ldsTag)[tid + i*64] = tg4[tid + i*64];
    __syncthreads();

    // gold: emissions (gathered) + transitions
    float g = 0.0f;
    #pragma unroll
    for (int it = 0; it < 16; it++){
        int t = tid + it*64;
        if (t < len){
            int tg = ldsTag[t];
            g += lgb[t*NT + tg];
            if (t >= 1) g += ldsT[ldsTag[t-1]*NT + tg];
        }
    }

    // v init = exp(emit_0), combine 8 chunk matrices in log-scaled space
    float v = fexp2(L2E * lgb[m]);
    float voff = 0.0f;

    const int n  = m;
    const int f  = n >> 4;
    const int hh = (n >> 3) & 1;
    const int di = f*4 + ((n >> 1) & 3);    // stored dword index holding row k=n

    for (int cc = 0; cc < 8; cc++){
        const int bcn = b*8 + cc;
        float offc = woff[bcn];             // wave-uniform chunk scale
        float w = flog2(v) + offc;          // per-element log2 magnitude
        float mw = w;
        #pragma unroll
        for (int d = 1; d <= 16; d <<= 1) mw = fmaxf(mw, __shfl_xor(mw, d, 64));
        float u = fexp2(w - mw);
        if (tid < 32) ldsU[m] = u;
        __syncthreads();

        const uint4* mp = (const uint4*)(wmat + (size_t)bcn*512 + di*64 + hh*32);
        float acc = 0.0f;
        #pragma unroll
        for (int qq = 0; qq < 8; qq++){
            uint4  md = mp[qq];
            float4 uu = ((const float4*)ldsU)[qq];
            float e0 = __builtin_bit_cast(float, (n&1) ? (md.x & 0xFFFF0000u) : (md.x << 16));
            float e1 = __builtin_bit_cast(float, (n&1) ? (md.y & 0xFFFF0000u) : (md.y << 16));
            float e2 = __builtin_bit_cast(float, (n&1) ? (md.z & 0xFFFF0000u) : (md.z << 16));
            float e3 = __builtin_bit_cast(float, (n&1) ? (md.w & 0xFFFF0000u) : (md.w << 16));
            acc = fmaf(e0, uu.x, acc);
            acc = fmaf(e1, uu.y, acc);
            acc = fmaf(e2, uu.z, acc);
            acc = fmaf(e3, uu.w, acc);
        }
        v = acc;
        voff += mw;
        __syncthreads();
    }

    float s = v;
    #pragma unroll
    for (int d = 1; d <= 16; d <<= 1) s += __shfl_xor(s, d, 64);   // sum over 32 tags
    #pragma unroll
    for (int d = 1; d <= 32; d <<= 1) g += __shfl_xor(g, d, 64);   // sum over 64 lanes
    if (tid == 0){
        float logz = LN2 * (voff + flog2(s));
        atomicAdd(out, (logz - g) * (1.0f / (float)NB));
    }
}

extern "C" void kernel_launch(void* const* d_in, const int* in_sizes, int n_in,
                              void* d_out, int out_size, void* d_ws, size_t ws_size,
                              hipStream_t stream) {
    const float* logits = (const float*)d_in[0];
    const float* trans  = (const float*)d_in[1];
    const int*   tags   = (const int*)d_in[2];
    const int*   lens   = (const int*)d_in[3];

    u32*   wmat = (u32*)d_ws;                        // 8192*512*4 = 16 MB
    float* woff = (float*)(wmat + 8192*512);         // 8192 floats

    hipMemsetAsync(d_out, 0, sizeof(float), stream);
    crf_chunk  <<<2048, 256, 0, stream>>>(logits, trans, wmat, woff);
    crf_combine<<<1024, 64, 0, stream>>>(logits, trans, tags, lens, wmat, woff,
                                         (float*)d_out);
}